// Round 7
// baseline (81.632 us; speedup 1.0000x reference)
//
#include <hip/hip_runtime.h>
#include <math.h>
#include <algorithm>
#include <string.h>

#define NATOM 20000
#define NEIGH 600000
#define NWAVE 8
#define NSPH 16
#define CAP 96   // fixed bucket capacity per atom (mean occupancy 30, P(>=96) ~ 1e-20)
// sortrec layout: [atom*CAP + rank] = float4 { asfloat(j), sx, sy, sz }
// emb4 layout:    [atom*8 + w] = float4 { coeff, alpha, center, 0 }
// cart4 layout:   [atom] = float4 { x, y, z, 0 }

struct CFT {
  float v[6][7][7];  // [jseq][m1+3][m2+3], zero where invalid
};

__device__ __forceinline__ float silu_f(float x) { return x / (1.f + expf(-x)); }

// ---------------- Kernel 0: zero the per-atom counters ----------------
__global__ __launch_bounds__(256) void zero_kernel(int* __restrict__ counts)
{
  int t = blockIdx.x * 256 + threadIdx.x;
  if (t < NATOM) counts[t] = 0;
}

// ---------------- Kernel 1: embedding MLP + packing + histogram (coalesced rank_n) ----------------
__global__ __launch_bounds__(256) void emb_hist_kernel(
    const float* __restrict__ species, const float* __restrict__ cart,
    const float* __restrict__ W1, const float* __restrict__ b1,
    const float* __restrict__ W2, const float* __restrict__ b2,
    const float* __restrict__ W3, const float* __restrict__ b3,
    float4* __restrict__ emb4, float4* __restrict__ cart4,
    const int* __restrict__ aidx, int* __restrict__ counts,
    int* __restrict__ rank_n)
{
  int t = blockIdx.x * 256 + threadIdx.x;
  if (t < NATOM) {
    float spv = species[t];
    float h1[16], h2[16], e24[24];
#pragma unroll
    for (int c = 0; c < 16; ++c) {
      float v = spv * W1[c] + b1[c];
      h1[c] = silu_f(v);
    }
#pragma unroll
    for (int d = 0; d < 16; ++d) {
      float v = b2[d];
#pragma unroll
      for (int c = 0; c < 16; ++c) v += h1[c] * W2[c * 16 + d];
      h2[d] = silu_f(v);
    }
#pragma unroll
    for (int e = 0; e < 24; ++e) {
      float v = b3[e];
#pragma unroll
      for (int c = 0; c < 16; ++c) v += h2[c] * W3[c * 24 + e];
      e24[e] = v;
    }
    float4* dst = emb4 + (size_t)t * 8;
#pragma unroll
    for (int w = 0; w < 8; ++w)
      dst[w] = make_float4(e24[w], e24[8 + w], e24[16 + w], 0.f);
    cart4[t] = make_float4(cart[t], cart[NATOM + t], cart[2 * NATOM + t], 0.f);
  }
  if (t < NEIGH) {
    int i = aidx[t];
    rank_n[t] = atomicAdd(&counts[i], 1);
  }
}

// ---------------- Kernel 2: scattered record write (no atomics, fire-and-forget stores) ----------------
__global__ __launch_bounds__(256) void scatter_kernel(
    const int* __restrict__ aidx, const float* __restrict__ shifts,
    const int* __restrict__ rank_n, float4* __restrict__ sortrec)
{
  int n = blockIdx.x * 256 + threadIdx.x;
  if (n >= NEIGH) return;
  int i = aidx[n];
  int slot = i * CAP + rank_n[n];
  float4 r;
  r.x = __int_as_float(aidx[NEIGH + n]);
  r.y = shifts[n];
  r.z = shifts[NEIGH + n];
  r.w = shifts[2 * NEIGH + n];
  sortrec[slot] = r;
}

// ---------------- Kernel 3: fused compute + accumulate + Wigner contraction ----------------
// 32 lanes per atom: sub = q*4 + wp; q in [0,8) walks slots base+q step 8,
// wp in [0,4) owns channels {wp, wp+4}. Software-pipelined gathers: next
// slot's record + its j-dependent cart4/emb4 loads issue before computing
// the current slot. q-partials combined via shfl_xor butterfly (bits 2,3,4).
__global__ __launch_bounds__(256) void fused_kernel(
    const float4* __restrict__ cart4, const float4* __restrict__ sortrec,
    const float4* __restrict__ emb4, const int* __restrict__ counts,
    float* __restrict__ out, CFT cf)
{
  int t = blockIdx.x * 256 + threadIdx.x;
  int a = t >> 5;         // grid is exact: NATOM*32/256
  int sub = t & 31;
  int wp = sub & 3;
  int q = sub >> 2;       // 0..7

  float4 ci = cart4[a];
  int s0 = a * CAP;
  int s1 = s0 + counts[a];

  float acc0[NSPH], acc1[NSPH];
#pragma unroll
  for (int k = 0; k < NSPH; ++k) { acc0[k] = 0.f; acc1[k] = 0.f; }

  const float SQ2 = 1.41421356237309515f;

  int s = s0 + q;
  bool valid = s < s1;
  float4 r  = make_float4(0.f, 0.f, 0.f, 0.f);
  float4 cj = r, e0 = r, e1 = r;
  if (valid) {
    r = sortrec[s];
    int j = __float_as_int(r.x);
    cj = cart4[j];
    e0 = emb4[(size_t)j * 8 + wp];
    e1 = emb4[(size_t)j * 8 + wp + 4];
  }

  while (valid) {
    // ---- prefetch next slot (independent of current compute) ----
    int sn = s + 8;
    bool vn = sn < s1;
    float4 rn  = make_float4(0.f, 0.f, 0.f, 0.f);
    float4 cjn = rn, e0n = rn, e1n = rn;
    if (vn) {
      rn = sortrec[sn];
      int jn = __float_as_int(rn.x);
      cjn = cart4[jn];
      e0n = emb4[(size_t)jn * 8 + wp];
      e1n = emb4[(size_t)jn * 8 + wp + 4];
    }

    // ---- compute current slot ----
    float cx = cj.x - ci.x + r.y;
    float cy = cj.y - ci.y + r.z;
    float cz = cj.z - ci.z + r.w;
    float d2 = cx * cx + cy * cy + cz * cz;
    float inv = __frsqrt_rn(d2);
    float dist = d2 * inv;
    float x = cx * inv, y = cy * inv, z = cz * inv;

    float cc = __cosf(dist * 0.62831853071795864769f);
    float cut0 = (cc + 1.f) * 0.5f;
    float cut = cut0 * cut0 * cut0;

    float sd0 = e0.y * (dist - e0.z);
    float av0 = cut * e0.x * __expf(-sd0 * sd0);
    float sd1 = e1.y * (dist - e1.z);
    float av1 = cut * e1.x * __expf(-sd1 * sd1);

    float r2 = x * x + y * y;
    float ri = __frsqrt_rn(fmaxf(r2, 1e-30f));
    float cp = x * ri, sp = y * ri;
    float c2 = cp * cp - sp * sp, s2 = 2.f * cp * sp;
    float c3 = c2 * cp - s2 * sp, s3 = s2 * cp + c2 * sp;

    float sz = sqrtf(fmaxf(1.f - z * z, 0.f));
    float P11 = -sz;
    float P22 = -3.f * sz * P11;
    float P33 = -5.f * sz * P22;
    float P10 = z;
    float P21 = 3.f * z * P11;
    float P32 = 5.f * z * P22;
    float P20 = (3.f * z * P10 - 1.f) * 0.5f;
    float P31 = (5.f * z * P21 - 3.f * P11) * 0.5f;
    float P30 = (5.f * z * P20 - 2.f * P10) * (1.f / 3.f);

    float sph[NSPH];
    sph[0]  = 0.28209479177387814f;
    sph[1]  = SQ2 * 0.3454941494713355f  * sp * P11;
    sph[2]  = 0.4886025119029199f * P10;
    sph[3]  = SQ2 * 0.3454941494713355f  * cp * P11;
    sph[4]  = SQ2 * 0.12875806734106326f * s2 * P22;
    sph[5]  = SQ2 * 0.25751613468212653f * sp * P21;
    sph[6]  = 0.6307831305050401f * P20;
    sph[7]  = SQ2 * 0.25751613468212653f * cp * P21;
    sph[8]  = SQ2 * 0.12875806734106326f * c2 * P22;
    sph[9]  = SQ2 * 0.027814921575518937f * s3 * P33;
    sph[10] = SQ2 * 0.06813236509555433f  * s2 * P32;
    sph[11] = SQ2 * 0.2154534560761003f   * sp * P31;
    sph[12] = 0.7463526651802308f * P30;
    sph[13] = SQ2 * 0.2154534560761003f   * cp * P31;
    sph[14] = SQ2 * 0.06813236509555433f  * c2 * P32;
    sph[15] = SQ2 * 0.027814921575518937f * c3 * P33;

#pragma unroll
    for (int k = 0; k < NSPH; ++k) {
      acc0[k] += sph[k] * av0;
      acc1[k] += sph[k] * av1;
    }

    // ---- rotate pipeline ----
    s = sn; valid = vn; r = rn; cj = cjn; e0 = e0n; e1 = e1n;
  }

  // combine the 8 q-partials (lane bits 2,3,4)
#pragma unroll
  for (int k = 0; k < NSPH; ++k) {
    acc0[k] += __shfl_xor(acc0[k], 4);
    acc0[k] += __shfl_xor(acc0[k], 8);
    acc0[k] += __shfl_xor(acc0[k], 16);
    acc1[k] += __shfl_xor(acc1[k], 4);
    acc1[k] += __shfl_xor(acc1[k], 8);
    acc1[k] += __shfl_xor(acc1[k], 16);
  }

  // Wigner contraction, fully unrolled static indices; lane q writes jj==q.
  constexpr int J0s[6] = {1, 1, 2, 2, 1, 3};
  constexpr int J1s[6] = {1, 1, 2, 2, 2, 3};
  constexpr int J2s[6] = {0, 2, 2, 0, 3, 2};
#pragma unroll
  for (int jj = 0; jj < 6; ++jj) {
    const int J0 = J0s[jj], J1 = J1s[jj], J2 = J2s[jj];
    const int n0 = J0 * (J0 + 1), n1 = J1 * (J1 + 1), n2 = J2 * (J2 + 1);
    float dj0 = 0.f, dj1 = 0.f;
#pragma unroll
    for (int m1 = -3; m1 <= 3; ++m1) {
      if (m1 < -J0 || m1 > J0) continue;
#pragma unroll
      for (int m2 = -3; m2 <= 3; ++m2) {
        if (m2 < -J1 || m2 > J1) continue;
        const int m3 = -m1 - m2;
        if (m3 < -J2 || m3 > J2) continue;
        const float w3 = cf.v[jj][m1 + 3][m2 + 3];
        dj0 += acc0[n0 + m1] * acc0[n1 + m2] * acc0[n2 + m3] * w3;
        dj1 += acc1[n0 + m1] * acc1[n1 + m2] * acc1[n2 + m3] * w3;
      }
    }
    if (q == jj) {
      out[((size_t)jj * NATOM + a) * 8 + wp]     = dj0;
      out[((size_t)jj * NATOM + a) * 8 + wp + 4] = dj1;
    }
  }
}

// ---------------- host: exact Wigner 3j (Racah) ----------------
static double dfact(int n) { double r = 1.0; for (int i = 2; i <= n; ++i) r *= i; return r; }
static double wig3j(int j1, int j2, int j3, int m1, int m2, int m3) {
  if (m1 + m2 + m3 != 0) return 0.0;
  double pre = sqrt(dfact(j1 + j2 - j3) * dfact(j1 - j2 + j3) * dfact(-j1 + j2 + j3)
                    / dfact(j1 + j2 + j3 + 1)
                    * dfact(j1 + m1) * dfact(j1 - m1) * dfact(j2 + m2) * dfact(j2 - m2)
                    * dfact(j3 + m3) * dfact(j3 - m3));
  int tmin = std::max(0, std::max(j2 - j3 - m1, j1 - j3 + m2));
  int tmax = std::min(j1 + j2 - j3, std::min(j1 - m1, j2 + m2));
  double s = 0.0;
  for (int t = tmin; t <= tmax; ++t)
    s += ((t & 1) ? -1.0 : 1.0) /
         (dfact(t) * dfact(j3 - j2 + m1 + t) * dfact(j3 - j1 - m2 + t) *
          dfact(j1 + j2 - j3 - t) * dfact(j1 - m1 - t) * dfact(j2 + m2 - t));
  int e = j1 - j2 - m3;
  double sgn = ((e % 2) != 0) ? -1.0 : 1.0;
  return sgn * pre * s;
}

extern "C" void kernel_launch(void* const* d_in, const int* in_sizes, int n_in,
                              void* d_out, int out_size, void* d_ws, size_t ws_size,
                              hipStream_t stream)
{
  const float* cart    = (const float*)d_in[0];
  const int*   aidx    = (const int*)d_in[1];
  const float* shifts  = (const float*)d_in[2];
  const float* species = (const float*)d_in[3];
  const float* W1 = (const float*)d_in[4];
  const float* b1 = (const float*)d_in[5];
  const float* W2 = (const float*)d_in[6];
  const float* b2 = (const float*)d_in[7];
  const float* W3 = (const float*)d_in[8];
  const float* b3 = (const float*)d_in[9];
  float* out = (float*)d_out;

  // ws layout: sortrec buckets | emb4 | cart4 | counts | rank_n
  float4* sortrec = (float4*)d_ws;                        // NATOM*CAP float4
  float4* emb4    = sortrec + (size_t)NATOM * CAP;        // NATOM*8 float4
  float4* cart4   = emb4 + (size_t)NATOM * 8;             // NATOM float4
  int*    counts  = (int*)(cart4 + NATOM);                // NATOM
  int*    rank_n  = counts + NATOM;                       // NEIGH

  // Dense Wigner-3j coefficient cube (deterministic, input-independent)
  static const int JS[6][3] = {{1,1,0},{1,1,2},{2,2,2},{2,2,0},{1,2,3},{3,3,2}};
  CFT cf;
  memset(&cf, 0, sizeof(cf));
  for (int j = 0; j < 6; ++j) {
    int J0 = JS[j][0], J1 = JS[j][1], J2 = JS[j][2];
    for (int m1 = -J0; m1 <= J0; ++m1)
      for (int m2 = std::max(-J2 - m1, -J1); m2 <= std::min(J2 - m1, J1); ++m2) {
        int m3 = -m1 - m2;
        cf.v[j][m1 + 3][m2 + 3] = (float)wig3j(J0, J1, J2, m1, m2, m3);
      }
  }

  zero_kernel<<<(NATOM + 255) / 256, 256, 0, stream>>>(counts);
  emb_hist_kernel<<<(NEIGH + 255) / 256, 256, 0, stream>>>(
      species, cart, W1, b1, W2, b2, W3, b3, emb4, cart4, aidx, counts, rank_n);
  scatter_kernel<<<(NEIGH + 255) / 256, 256, 0, stream>>>(aidx, shifts, rank_n, sortrec);
  fused_kernel<<<(NATOM * 32) / 256, 256, 0, stream>>>(
      cart4, sortrec, emb4, counts, out, cf);
}